// Round 9
// baseline (4098.498 us; speedup 1.0000x reference)
//
#include <hip/hip_runtime.h>

// NODE decoder, round 7 design (resubmit; weight-streaming has never executed
// due to repeated GPU-acquisition timeouts). Split-fp16 MFMA integrator,
// WEIGHTS STREAMED FROM L2.
// R6 result: passed, absmax 0.03125 (= fp32 noise floor), 2250 us, MfmaUtil
// 15.7%, Occupancy 23% -> register-hoisted weights (128 VGPR) pushed unified
// reg use to ~256/wave -> 2 waves/SIMD -> latency-bound (84% stall).
// Fix: prep packs weight fragments in per-(wave,kt,lane) order; ode loads them
// per stage as coalesced dwordx4 from L2 (weights 320KB, L2/L3-resident).
// VGPR drops to ~105-110 (enforced by __launch_bounds__(512,4)) -> 16 waves/CU.
// Numerics unchanged: x.w = xh.wh + 2^-11*(xl.wh + xh.wl), LN/state/RK4 fp32.

#define TSTEPS 32
#define BATCH  16384
#define LAT    128
#define HID    256
#define NOUT   8

using f16x8  = __attribute__((ext_vector_type(8)))  _Float16;
using f16x4  = __attribute__((ext_vector_type(4)))  _Float16;
using f32x16 = __attribute__((ext_vector_type(16))) float;
using f32x4v = __attribute__((ext_vector_type(4)))  float;

#define LO_S 2048.0f            // lo-part pre-scale (2^11)
#define LO_I 4.8828125e-4f      // 2^-11

// ---------------------------------------------------------------------------
// Weight prep: pack fragments in the EXACT per-(wave,kt,lane) order the ode
// kernel consumes, so each fragment load is one coalesced dwordx4.
//   w1 frag value for (wv,kt,lane,j):  row = 32*wv + (lane&31)          [hid]
//                                      k   = kt*16 + 8*(lane>>5) + j    [lat]
//   w2 frag value for (wv,kt,lane,j):  t2=wv>>1, kh=wv&1
//                                      row = 32*t2 + (lane&31)          [lat]
//                                      k   = (8*kh+kt)*16 + 8*(lane>>5)+j [hid]
// grid = 128 x 256.
// ---------------------------------------------------------------------------
__global__ void prep_kernel(const float* __restrict__ W1, const float* __restrict__ b1,
                            const float* __restrict__ g1, const float* __restrict__ be1,
                            const float* __restrict__ W2, const float* __restrict__ b2,
                            const float* __restrict__ g2, const float* __restrict__ be2,
                            const float* __restrict__ Wl,
                            _Float16* __restrict__ w1h, _Float16* __restrict__ w1l,
                            _Float16* __restrict__ w2h, _Float16* __restrict__ w2l,
                            _Float16* __restrict__ wlt,
                            float2* __restrict__ pA, float2* __restrict__ pB,
                            float2* __restrict__ pD, float* __restrict__ b2f)
{
    const int i = blockIdx.x * 256 + threadIdx.x;    // [0, 32768)
    const int j    = i & 7;
    const int lane = (i >> 3) & 63;
    const int kt   = (i >> 9) & 7;
    const int wv   = i >> 12;
    {   // w1 fragment-packed hi/lo (k rows 0..127 of W1; row 128 = time, fp32 path)
        const int row = 32 * wv + (lane & 31);
        const int k   = kt * 16 + 8 * (lane >> 5) + j;
        const float v = W1[k * 256 + row];
        const _Float16 vh = (_Float16)v;
        w1h[i] = vh;
        w1l[i] = (_Float16)((v - (float)vh) * LO_S);
    }
    {   // w2 fragment-packed hi/lo
        const int t2 = wv >> 1, kh = wv & 1;
        const int row = 32 * t2 + (lane & 31);
        const int k   = (8 * kh + kt) * 16 + 8 * (lane >> 5) + j;
        const float v = W2[k * 128 + row];
        const _Float16 vh = (_Float16)v;
        w2h[i] = vh;
        w2l[i] = (_Float16)((v - (float)vh) * LO_S);
    }
    {   // WlT[hid][lat] (hi only - decode is not amplification-sensitive)
        const int h = i >> 7, k = i & 127;
        wlt[i] = (_Float16)Wl[k * 256 + h];
    }
    if (i < 256) {
        pA[i] = make_float2(b1[i], W1[128 * 256 + i]);   // {b1, w1_time} fp32
        pB[i] = make_float2(g1[i], be1[i]);
    }
    if (i < 128) {
        pD[i] = make_float2(g2[i], be2[i]);
        b2f[i] = b2[i];
    }
}

// ---------------------------------------------------------------------------
// ODE kernel. 512 blocks x 512 thr (8 waves), 32 samples/block.
// C/D layout (HW-verified): col=lane&31(=sample),
// row = (reg&3) + 8*(reg>>2) + 4*(lane>>5).
// __launch_bounds__(512,4): cap unified regs at 128 -> 16 waves/CU (2 blk/CU).
// ---------------------------------------------------------------------------
__global__ __launch_bounds__(512, 4) void ode_kernel(
    const float* __restrict__ z0, const float* __restrict__ ts,
    const _Float16* __restrict__ w1hg, const _Float16* __restrict__ w1lg,
    const _Float16* __restrict__ w2hg, const _Float16* __restrict__ w2lg,
    const float2* __restrict__ pAg, const float2* __restrict__ pBg,
    const float2* __restrict__ pDg, const float* __restrict__ b2g,
    float* __restrict__ zs)
{
    __shared__ _Float16 ztH[32 * 128], ztLo[32 * 128];   // stage arg [samp][lat], swizzled
    __shared__ _Float16 a1H[32 * 256], a1Lo[32 * 256];   // layer-1 act, swizzled
    __shared__ float    pt[4096];                        // GEMM2 partials / z-transpose
    __shared__ float    scrS[8][33], scrQ[8][33];        // LN cross-wave stats
    __shared__ float2   pA[256], pB[256], pD[128];
    __shared__ float    b2s[128];

    const int tid  = threadIdx.x;
    const int w    = tid >> 6;          // wave 0..7
    const int l    = tid & 63;
    const int li   = l & 31;            // sample (= MFMA col)
    const int lh   = l >> 5;
    const int samp = li;
    const int t2   = w >> 1;            // GEMM2 tile
    const int kh   = w & 1;             // GEMM2 k-half
    const long gsamp = (long)blockIdx.x * 32 + li;
    char* ztHB = (char*)ztH;  char* ztLB = (char*)ztLo;
    char* a1HB = (char*)a1H;  char* a1LB = (char*)a1Lo;

    if (tid < 256) { pA[tid] = pAg[tid]; pB[tid] = pBg[tid]; }
    if (tid < 128) { pD[tid] = pDg[tid]; b2s[tid] = b2g[tid]; }

    // fragment-packed weight views; wave w's kt-th fragment = v[(w*8+kt)*64 + l]
    const f16x8* w1hv = (const f16x8*)w1hg;
    const f16x8* w1lv = (const f16x8*)w1lg;
    const f16x8* w2hv = (const f16x8*)w2hg;
    const f16x8* w2lv = (const f16x8*)w2lg;
    const int fbase = w * 8 * 64 + l;   // + kt*64

    // ---- z state (owner waves kh==0 hold lats [32*t2, 32*t2+32)) ----
    float zor[16], znw[16];
    if (kh == 0) {
        #pragma unroll
        for (int rg = 0; rg < 4; ++rg) {
            const int lat0 = 32 * t2 + 8 * rg + 4 * lh;
            f32x4v v = *(const f32x4v*)(z0 + gsamp * 128 + lat0);
            f16x4 hv, lv;
            #pragma unroll
            for (int j = 0; j < 4; ++j) {
                zor[rg * 4 + j] = v[j];
                hv[j] = (_Float16)v[j];
                lv[j] = (_Float16)((v[j] - (float)hv[j]) * LO_S);
            }
            const int slot = lat0 >> 3;
            const int bo = samp * 256 + ((slot ^ (samp & 15)) << 4) + 8 * lh;
            *(f16x4*)(ztHB + bo) = hv;
            *(f16x4*)(ztLB + bo) = lv;
        }
    }
    __syncthreads();

    #pragma unroll 1
    for (int step = 0; step < TSTEPS; ++step) {
        const float tc = (step == 0) ? 0.f : ts[(long)(step - 1) * BATCH + gsamp];
        const float tn = ts[(long)step * BATCH + gsamp];
        const float dt = tn - tc;
        if (kh == 0) {
            #pragma unroll
            for (int i = 0; i < 16; ++i) znw[i] = zor[i];
        }

        #pragma unroll 1
        for (int stg = 0; stg < 4; ++stg) {
            const float tstg = (stg == 0) ? tc : (stg == 3) ? tn : fmaf(0.5f, dt, tc);
            // ---------------- GEMM1 (3-product, streamed frags) --------------
            f32x16 ah = {}, al = {};
            #pragma unroll
            for (int kt = 0; kt < 8; ++kt) {
                const f16x8 wh = w1hv[fbase + kt * 64];
                const f16x8 wl = w1lv[fbase + kt * 64];
                const int kc = kt * 2 + lh;
                const int bo = samp * 256 + ((kc ^ (samp & 15)) << 4);
                f16x8 bh = *(const f16x8*)(ztHB + bo);
                f16x8 bl = *(const f16x8*)(ztLB + bo);
                ah = __builtin_amdgcn_mfma_f32_32x32x16_f16(wh, bh, ah, 0, 0, 0);
                al = __builtin_amdgcn_mfma_f32_32x32x16_f16(wl, bh, al, 0, 0, 0);
                al = __builtin_amdgcn_mfma_f32_32x32x16_f16(wh, bl, al, 0, 0, 0);
            }
            // epilogue: h = hi + 2^-11*lo + b1 + t*w1_time  (in place, fp32)
            float s = 0.f, q = 0.f;
            #pragma unroll
            for (int rg = 0; rg < 4; ++rg) {
                #pragma unroll
                for (int j = 0; j < 4; ++j) {
                    const int hid = 32 * w + 8 * rg + 4 * lh + j;
                    const float2 ab = pA[hid];
                    float h = ah[rg * 4 + j] + LO_I * al[rg * 4 + j] + fmaf(tstg, ab.y, ab.x);
                    ah[rg * 4 + j] = h;
                    s += h; q += h * h;
                }
            }
            s += __shfl_xor(s, 32);
            q += __shfl_xor(q, 32);
            if (l < 32) { scrS[w][samp] = s; scrQ[w][samp] = q; }
            __syncthreads();                                  // A: LN1 stats ready
            {
                float ssum = 0.f, qsum = 0.f;
                #pragma unroll
                for (int ww = 0; ww < 8; ++ww) { ssum += scrS[ww][samp]; qsum += scrQ[ww][samp]; }
                const float mu = ssum * (1.f / 256.f);
                const float rs = rsqrtf(qsum * (1.f / 256.f) - mu * mu + 1e-5f);
                #pragma unroll
                for (int rg = 0; rg < 4; ++rg) {
                    f16x4 hv, lv;
                    #pragma unroll
                    for (int j = 0; j < 4; ++j) {
                        const int hid = 32 * w + 8 * rg + 4 * lh + j;
                        const float2 gb = pB[hid];
                        float a = fmaf((ah[rg * 4 + j] - mu) * rs, gb.x, gb.y);
                        a = fmaxf(a, 0.1f * a);               // LeakyReLU(0.1)
                        hv[j] = (_Float16)a;
                        lv[j] = (_Float16)((a - (float)hv[j]) * LO_S);
                    }
                    const int slot = 4 * w + rg;
                    const int bo = samp * 512 + ((slot ^ (samp & 31)) << 4) + 8 * lh;
                    *(f16x4*)(a1HB + bo) = hv;
                    *(f16x4*)(a1LB + bo) = lv;
                }
            }
            __syncthreads();                                  // B: a1 ready
            // ---------------- GEMM2 (3-product, k-split, streamed frags) -----
            f32x16 ch = {}, cl = {};
            #pragma unroll
            for (int kt = 0; kt < 8; ++kt) {
                const f16x8 wh = w2hv[fbase + kt * 64];
                const f16x8 wl = w2lv[fbase + kt * 64];
                const int kc = (8 * kh + kt) * 2 + lh;
                const int bo = samp * 512 + ((kc ^ (samp & 31)) << 4);
                f16x8 bh = *(const f16x8*)(a1HB + bo);
                f16x8 bl = *(const f16x8*)(a1LB + bo);
                ch = __builtin_amdgcn_mfma_f32_32x32x16_f16(wh, bh, ch, 0, 0, 0);
                cl = __builtin_amdgcn_mfma_f32_32x32x16_f16(wl, bh, cl, 0, 0, 0);
                cl = __builtin_amdgcn_mfma_f32_32x32x16_f16(wh, bl, cl, 0, 0, 0);
            }
            if (kh == 1) {                                    // upper k-half -> partials
                #pragma unroll
                for (int rg = 0; rg < 4; ++rg)
                    #pragma unroll
                    for (int j = 0; j < 4; ++j) {
                        const int row = 8 * rg + 4 * lh + j;
                        pt[(t2 * 32 + row) * 32 + samp] =
                            ch[rg * 4 + j] + LO_I * cl[rg * 4 + j];
                    }
            }
            __syncthreads();                                  // C: partials ready
            float h2[16];
            if (kh == 0) {
                float s2 = 0.f, q2 = 0.f;
                #pragma unroll
                for (int rg = 0; rg < 4; ++rg) {
                    #pragma unroll
                    for (int j = 0; j < 4; ++j) {
                        const int row = 8 * rg + 4 * lh + j;
                        const float v = ch[rg * 4 + j] + LO_I * cl[rg * 4 + j]
                                      + pt[(t2 * 32 + row) * 32 + samp]
                                      + b2s[32 * t2 + row];
                        h2[rg * 4 + j] = v;
                        s2 += v; q2 += v * v;
                    }
                }
                s2 += __shfl_xor(s2, 32);
                q2 += __shfl_xor(q2, 32);
                if (l < 32) { scrS[t2][samp] = s2; scrQ[t2][samp] = q2; }
            }
            __syncthreads();                                  // D: LN2 stats ready
            if (kh == 0) {
                float ssum = 0.f, qsum = 0.f;
                #pragma unroll
                for (int tt = 0; tt < 4; ++tt) { ssum += scrS[tt][samp]; qsum += scrQ[tt][samp]; }
                const float mu2 = ssum * (1.f / 128.f);
                const float rs2 = rsqrtf(qsum * (1.f / 128.f) - mu2 * mu2 + 1e-5f);
                const float c6  = (stg == 1 || stg == 2) ? (1.f / 3.f) : (1.f / 6.f);
                const float cnx = (stg < 2) ? 0.5f : 1.f;
                #pragma unroll
                for (int rg = 0; rg < 4; ++rg) {
                    f16x4 hv, lv;
                    #pragma unroll
                    for (int j = 0; j < 4; ++j) {
                        const int i = rg * 4 + j;
                        const int lat = 32 * t2 + 8 * rg + 4 * lh + j;
                        const float2 gb = pD[lat];
                        float a = fmaf((h2[i] - mu2) * rs2, gb.x, gb.y);
                        a = fmaxf(a, 0.1f * a);               // k (stage derivative)
                        znw[i] = fmaf(dt * c6, a, znw[i]);
                        const float za = (stg < 3) ? fmaf(cnx * dt, a, zor[i]) : znw[i];
                        hv[j] = (_Float16)za;
                        lv[j] = (_Float16)((za - (float)hv[j]) * LO_S);
                        if (stg == 3) {
                            // swizzled z-transpose for coalesced global store
                            pt[lat * 32 + (samp ^ (lat & 31))] = za;
                            zor[i] = za;
                        }
                    }
                    const int slot = 4 * t2 + rg;
                    const int bo = samp * 256 + ((slot ^ (samp & 15)) << 4) + 8 * lh;
                    *(f16x4*)(ztHB + bo) = hv;
                    *(f16x4*)(ztLB + bo) = lv;
                }
            }
            __syncthreads();                                  // E: ztL (+ptZ) ready
        }
        // ---- cooperative coalesced zs store (from pt z-transpose) ----
        const long zrow = (long)step * BATCH + (long)blockIdx.x * 32;
        for (int ii = tid; ii < 1024; ii += 512) {
            const int sp = ii >> 5, lat0 = (ii & 31) * 4;
            f32x4v v;
            #pragma unroll
            for (int j = 0; j < 4; ++j)
                v[j] = pt[(lat0 + j) * 32 + (sp ^ ((lat0 + j) & 31))];
            *(f32x4v*)(zs + (zrow + sp) * 128 + lat0) = v;
        }
    }
}

// ---------------------------------------------------------------------------
// Decode: hs = leaky(zs@Wl+bl); xs = hs@Wo+bo.  fp16 MFMA (no split needed).
// grid = T*B/32 = 16384 blocks x 512 thr.  (unchanged from verified R6)
// ---------------------------------------------------------------------------
__global__ __launch_bounds__(512, 4) void dec_kernel(
    const float* __restrict__ zsin, const _Float16* __restrict__ wlt,
    const float* __restrict__ bl, const float* __restrict__ Wo,
    const float* __restrict__ bo, float* __restrict__ xs)
{
    __shared__ _Float16 zH[32 * 128];      // [row][lat] swizzled
    __shared__ float wo4[256][8];          // [hid][o]
    __shared__ float bl_s[256];
    __shared__ float scrX[8][32][8];       // [wave][row][o]
    __shared__ float bo_s[8];

    const int tid = threadIdx.x;
    const int w = tid >> 6, l = tid & 63, li = l & 31, lh = l >> 5;
    const long r0 = (long)blockIdx.x * 32;
    char* zB = (char*)zH;

    if (tid < 256) bl_s[tid] = bl[tid];
    for (int i = tid; i < 256 * 8; i += 512) wo4[i >> 3][i & 7] = Wo[i];
    if (tid < 8) bo_s[tid] = bo[tid];

    // stage 32 zs rows -> fp16 swizzled LDS (coalesced f32x4 loads)
    for (int ii = tid; ii < 1024; ii += 512) {
        const int row = ii >> 5, lat0 = (ii & 31) * 4;
        f32x4v v = *(const f32x4v*)(zsin + (r0 + row) * 128 + lat0);
        f16x4 hv;
        #pragma unroll
        for (int j = 0; j < 4; ++j) hv[j] = (_Float16)v[j];
        const int slot = lat0 >> 3;
        *(f16x4*)(zB + row * 256 + ((slot ^ (row & 15)) << 4) + (lat0 & 7) * 2) = hv;
    }

    f16x8 wl8[8];
    #pragma unroll
    for (int kt = 0; kt < 8; ++kt)
        wl8[kt] = *(const f16x8*)(wlt + (32 * w + li) * 128 + kt * 16 + lh * 8);
    __syncthreads();

    f32x16 acc = {};
    #pragma unroll
    for (int kt = 0; kt < 8; ++kt) {
        const int kc = kt * 2 + lh;
        f16x8 b = *(const f16x8*)(zB + li * 256 + ((kc ^ (li & 15)) << 4));
        acc = __builtin_amdgcn_mfma_f32_32x32x16_f16(wl8[kt], b, acc, 0, 0, 0);
    }

    float xo[8];
    #pragma unroll
    for (int o = 0; o < 8; ++o) xo[o] = 0.f;
    #pragma unroll
    for (int rg = 0; rg < 4; ++rg) {
        #pragma unroll
        for (int j = 0; j < 4; ++j) {
            const int hid = 32 * w + 8 * rg + 4 * lh + j;
            float a = acc[rg * 4 + j] + bl_s[hid];
            a = fmaxf(a, 0.1f * a);
            const float4 wa = *(const float4*)&wo4[hid][0];   // broadcast reads
            const float4 wb = *(const float4*)&wo4[hid][4];
            xo[0] = fmaf(a, wa.x, xo[0]); xo[1] = fmaf(a, wa.y, xo[1]);
            xo[2] = fmaf(a, wa.z, xo[2]); xo[3] = fmaf(a, wa.w, xo[3]);
            xo[4] = fmaf(a, wb.x, xo[4]); xo[5] = fmaf(a, wb.y, xo[5]);
            xo[6] = fmaf(a, wb.z, xo[6]); xo[7] = fmaf(a, wb.w, xo[7]);
        }
    }
    #pragma unroll
    for (int o = 0; o < 8; ++o) xo[o] += __shfl_xor(xo[o], 32);
    if (l < 32) {
        *(float4*)&scrX[w][li][0] = make_float4(xo[0], xo[1], xo[2], xo[3]);
        *(float4*)&scrX[w][li][4] = make_float4(xo[4], xo[5], xo[6], xo[7]);
    }
    __syncthreads();
    if (tid < 256) {
        const int row = tid >> 3, o = tid & 7;
        float s = bo_s[o];
        #pragma unroll
        for (int ww = 0; ww < 8; ++ww) s += scrX[ww][row][o];
        xs[(r0 + row) * 8 + o] = s;
    }
}

extern "C" void kernel_launch(void* const* d_in, const int* in_sizes, int n_in,
                              void* d_out, int out_size, void* d_ws, size_t ws_size,
                              hipStream_t stream) {
    const float* z0  = (const float*)d_in[0];
    const float* ts  = (const float*)d_in[1];
    const float* W1  = (const float*)d_in[2];
    const float* b1  = (const float*)d_in[3];
    const float* g1  = (const float*)d_in[4];
    const float* be1 = (const float*)d_in[5];
    const float* W2  = (const float*)d_in[6];
    const float* b2  = (const float*)d_in[7];
    const float* g2  = (const float*)d_in[8];
    const float* be2 = (const float*)d_in[9];
    const float* Wl  = (const float*)d_in[10];
    const float* bl  = (const float*)d_in[11];
    const float* Wo  = (const float*)d_in[12];
    const float* bo  = (const float*)d_in[13];

    float* xs = (float*)d_out;                                  // [T,B,8]
    float* zs = (float*)d_out + (size_t)TSTEPS * BATCH * NOUT;  // [T,B,128]

    // workspace layout (all f16 arrays first; 8B-aligned tail)
    _Float16* w1h = (_Float16*)d_ws;                  // [8][8][64][8] frag-packed
    _Float16* w1l = w1h + 32768;
    _Float16* w2h = w1l + 32768;                      // [8][8][64][8] frag-packed
    _Float16* w2l = w2h + 32768;
    _Float16* wlt = w2l + 32768;                      // [256][128]
    float2* pA  = (float2*)(wlt + 32768);             // [256] {b1, w1_time}
    float2* pB  = pA + 256;                           // [256] {g1, be1}
    float2* pD  = pB + 256;                           // [128] {g2, be2}
    float*  b2f = (float*)(pD + 128);                 // [128]

    prep_kernel<<<dim3(128), dim3(256), 0, stream>>>(
        W1, b1, g1, be1, W2, b2, g2, be2, Wl,
        w1h, w1l, w2h, w2l, wlt, pA, pB, pD, b2f);
    ode_kernel<<<dim3(BATCH / 32), dim3(512), 0, stream>>>(
        z0, ts, w1h, w1l, w2h, w2l, pA, pB, pD, b2f, zs);
    dec_kernel<<<dim3(TSTEPS * BATCH / 32), dim3(512), 0, stream>>>(
        zs, wlt, bl, Wo, bo, xs);
}